// Round 1
// baseline (344.564 us; speedup 1.0000x reference)
//
#include <hip/hip_runtime.h>

#define D_FEAT 96
#define P_DIM 96
#define OUT_DIM 192

// Zero the output (feature half needs accumulate-from-zero; prompt half gets
// overwritten anyway) and the in-degree scratch. Harness poisons with 0xAA.
__global__ __launch_bounds__(256) void zero_k(float* __restrict__ out,
                                              float* __restrict__ deg,
                                              int n_out, int n_deg) {
    int stride = gridDim.x * blockDim.x;
    for (int i = blockIdx.x * blockDim.x + threadIdx.x; i < n_out; i += stride)
        out[i] = 0.0f;
    for (int i = blockIdx.x * blockDim.x + threadIdx.x; i < n_deg; i += stride)
        deg[i] = 0.0f;
}

// in_deg[v] = number of edges with dst == v
__global__ __launch_bounds__(256) void deg_k(const int* __restrict__ dst,
                                             float* __restrict__ deg,
                                             int n_edges) {
    int e = blockIdx.x * blockDim.x + threadIdx.x;
    if (e < n_edges) atomicAdd(deg + dst[e], 1.0f);
}

// One thread per (edge, feature-col): out[dst[e]*192 + c] += emb[src[e]*96 + c]
// 96 consecutive threads share an edge -> coalesced row reads, broadcast idx loads.
__global__ __launch_bounds__(256) void scatter_k(const float* __restrict__ emb,
                                                 const int* __restrict__ src,
                                                 const int* __restrict__ dst,
                                                 float* __restrict__ out,
                                                 int n_edges) {
    int idx = blockIdx.x * blockDim.x + threadIdx.x;
    int e = idx / D_FEAT;
    if (e >= n_edges) return;
    int c = idx - e * D_FEAT;
    int s = src[e];
    int d = dst[e];
    atomicAdd(out + (size_t)d * OUT_DIM + c, emb[(size_t)s * D_FEAT + c]);
}

// out[v*192 + 96 + c] = deg[v] * weight[c]
__global__ __launch_bounds__(256) void prompt_k(const float* __restrict__ w,
                                                const float* __restrict__ deg,
                                                float* __restrict__ out,
                                                int n_nodes) {
    int idx = blockIdx.x * blockDim.x + threadIdx.x;
    if (idx >= n_nodes * P_DIM) return;
    int v = idx / P_DIM;
    int c = idx - v * P_DIM;
    out[(size_t)v * OUT_DIM + P_DIM + c] = deg[v] * w[c];
}

extern "C" void kernel_launch(void* const* d_in, const int* in_sizes, int n_in,
                              void* d_out, int out_size, void* d_ws, size_t ws_size,
                              hipStream_t stream) {
    const float* emb = (const float*)d_in[0];   // [N, 96] f32
    const float* w   = (const float*)d_in[1];   // [1, 96] f32
    const int*   src = (const int*)d_in[2];     // [E] int32 (jax demotes int64)
    const int*   dst = (const int*)d_in[3];     // [E] int32
    float* out = (float*)d_out;                 // [N, 192] f32
    float* deg = (float*)d_ws;                  // [N] f32 scratch

    const int n_nodes = in_sizes[0] / D_FEAT;
    const int n_edges = in_sizes[2];
    const int n_out   = n_nodes * OUT_DIM;

    {
        int threads = 256;
        int blocks = (n_out + threads - 1) / threads;
        if (blocks > 2048) blocks = 2048;  // grid-stride
        zero_k<<<blocks, threads, 0, stream>>>(out, deg, n_out, n_nodes);
    }
    {
        int threads = 256;
        int blocks = (n_edges + threads - 1) / threads;
        deg_k<<<blocks, threads, 0, stream>>>(dst, deg, n_edges);
    }
    {
        int threads = 256;
        long long total = (long long)n_edges * D_FEAT;
        int blocks = (int)((total + threads - 1) / threads);
        scatter_k<<<blocks, threads, 0, stream>>>(emb, src, dst, out, n_edges);
    }
    {
        int threads = 256;
        int blocks = (n_nodes * P_DIM + threads - 1) / threads;
        prompt_k<<<blocks, threads, 0, stream>>>(w, deg, out, n_nodes);
    }
}

// Round 2
// 173.078 us; speedup vs baseline: 1.9908x; 1.9908x over previous
//
#include <hip/hip_runtime.h>

#define D_FEAT 96
#define P_DIM 96
#define OUT_DIM 192
#define SCAN_BLK 256

// ---------------- fallback (round-1) kernels: used only if ws too small ----
__global__ __launch_bounds__(256) void zero_k(float* __restrict__ out,
                                              float* __restrict__ deg,
                                              int n_out, int n_deg) {
    int stride = gridDim.x * blockDim.x;
    for (int i = blockIdx.x * blockDim.x + threadIdx.x; i < n_out; i += stride)
        out[i] = 0.0f;
    for (int i = blockIdx.x * blockDim.x + threadIdx.x; i < n_deg; i += stride)
        deg[i] = 0.0f;
}

__global__ __launch_bounds__(256) void degf_k(const int* __restrict__ dst,
                                              float* __restrict__ deg,
                                              int n_edges) {
    int e = blockIdx.x * blockDim.x + threadIdx.x;
    if (e < n_edges) atomicAdd(deg + dst[e], 1.0f);
}

__global__ __launch_bounds__(256) void scatter_k(const float* __restrict__ emb,
                                                 const int* __restrict__ src,
                                                 const int* __restrict__ dst,
                                                 float* __restrict__ out,
                                                 int n_edges) {
    int idx = blockIdx.x * blockDim.x + threadIdx.x;
    int e = idx / D_FEAT;
    if (e >= n_edges) return;
    int c = idx - e * D_FEAT;
    atomicAdd(out + (size_t)dst[e] * OUT_DIM + c, emb[(size_t)src[e] * D_FEAT + c]);
}

__global__ __launch_bounds__(256) void prompt_k(const float* __restrict__ w,
                                                const float* __restrict__ deg,
                                                float* __restrict__ out,
                                                int n_nodes) {
    int idx = blockIdx.x * blockDim.x + threadIdx.x;
    if (idx >= n_nodes * P_DIM) return;
    int v = idx / P_DIM;
    int c = idx - v * P_DIM;
    out[(size_t)v * OUT_DIM + P_DIM + c] = deg[v] * w[c];
}

// ---------------- sorted-CSR path ------------------------------------------

// hist[i] = 0
__global__ __launch_bounds__(256) void hist0_k(int* __restrict__ hist, int n) {
    int i = blockIdx.x * blockDim.x + threadIdx.x;
    if (i < n) hist[i] = 0;
}

// hist[dst[e]]++
__global__ __launch_bounds__(256) void hist_k(const int* __restrict__ dst,
                                              int* __restrict__ hist, int n_edges) {
    int e = blockIdx.x * blockDim.x + threadIdx.x;
    if (e < n_edges) atomicAdd(hist + dst[e], 1);
}

// per-block exclusive scan; aux[b] = block sum
__global__ __launch_bounds__(SCAN_BLK) void scan_block_k(const int* __restrict__ hist,
                                                         int* __restrict__ offs,
                                                         int* __restrict__ aux, int n) {
    __shared__ int buf[SCAN_BLK];
    int t = threadIdx.x;
    int i = blockIdx.x * SCAN_BLK + t;
    int v = (i < n) ? hist[i] : 0;
    buf[t] = v;
    __syncthreads();
    for (int off = 1; off < SCAN_BLK; off <<= 1) {
        int x = (t >= off) ? buf[t - off] : 0;
        __syncthreads();
        buf[t] += x;
        __syncthreads();
    }
    if (i < n) offs[i] = buf[t] - v;          // exclusive within block
    if (t == SCAN_BLK - 1) aux[blockIdx.x] = buf[t];
}

// single-block exclusive scan of aux[nb] in place (nb <= SCAN_BLK)
__global__ __launch_bounds__(SCAN_BLK) void scan_aux_k(int* __restrict__ aux, int nb) {
    __shared__ int buf[SCAN_BLK];
    int t = threadIdx.x;
    int v = (t < nb) ? aux[t] : 0;
    buf[t] = v;
    __syncthreads();
    for (int off = 1; off < SCAN_BLK; off <<= 1) {
        int x = (t >= off) ? buf[t - off] : 0;
        __syncthreads();
        buf[t] += x;
        __syncthreads();
    }
    if (t < nb) aux[t] = buf[t] - v;          // exclusive
}

// offs[i] += aux[block]; cursor[i] = offs[i]
__global__ __launch_bounds__(SCAN_BLK) void scan_add_k(int* __restrict__ offs,
                                                       const int* __restrict__ aux,
                                                       int* __restrict__ cursor, int n) {
    int i = blockIdx.x * SCAN_BLK + threadIdx.x;
    if (i < n) {
        int o = offs[i] + aux[blockIdx.x];
        offs[i] = o;
        cursor[i] = o;
    }
}

// sorted_src[pos] = src[e], pos from per-dst cursor
__global__ __launch_bounds__(256) void scatter_sort_k(const int* __restrict__ src,
                                                      const int* __restrict__ dst,
                                                      int* __restrict__ cursor,
                                                      int* __restrict__ sorted_src,
                                                      int n_edges) {
    int e = blockIdx.x * blockDim.x + threadIdx.x;
    if (e < n_edges) {
        int pos = atomicAdd(cursor + dst[e], 1);
        sorted_src[pos] = src[e];
    }
}

// one node per 96 threads: register-accumulate feature half, fuse prompt half
__global__ __launch_bounds__(192) void agg_k(const float* __restrict__ emb,
                                             const float* __restrict__ w,
                                             const int* __restrict__ offs,
                                             const int* __restrict__ hist,
                                             const int* __restrict__ sorted_src,
                                             float* __restrict__ out, int n_nodes) {
    int t = threadIdx.x;
    int node = blockIdx.x * 2 + t / 96;
    int col = t - (t / 96) * 96;
    if (node >= n_nodes) return;

    int start = offs[node];
    int cnt = hist[node];
    float wc = w[col];

    float acc0 = 0.0f, acc1 = 0.0f;
    int j = 0;
    for (; j + 1 < cnt; j += 2) {           // 2 independent loads in flight
        int s0 = sorted_src[start + j];
        int s1 = sorted_src[start + j + 1];
        acc0 += emb[(size_t)s0 * D_FEAT + col];
        acc1 += emb[(size_t)s1 * D_FEAT + col];
    }
    if (j < cnt) {
        int s0 = sorted_src[start + j];
        acc0 += emb[(size_t)s0 * D_FEAT + col];
    }

    size_t base = (size_t)node * OUT_DIM;
    out[base + col] = acc0 + acc1;
    out[base + P_DIM + col] = (float)cnt * wc;
}

extern "C" void kernel_launch(void* const* d_in, const int* in_sizes, int n_in,
                              void* d_out, int out_size, void* d_ws, size_t ws_size,
                              hipStream_t stream) {
    const float* emb = (const float*)d_in[0];   // [N, 96] f32
    const float* w   = (const float*)d_in[1];   // [1, 96] f32
    const int*   src = (const int*)d_in[2];     // [E] int32
    const int*   dst = (const int*)d_in[3];     // [E] int32
    float* out = (float*)d_out;                 // [N, 192] f32

    const int n_nodes = in_sizes[0] / D_FEAT;
    const int n_edges = in_sizes[2];
    const int nb = (n_nodes + SCAN_BLK - 1) / SCAN_BLK;   // scan blocks

    // ws layout (int32): hist[N] | offs[N] | cursor[N] | aux[SCAN_BLK] | sorted_src[E]
    size_t need = ((size_t)3 * n_nodes + SCAN_BLK + n_edges) * sizeof(int);

    if (ws_size < need || nb > SCAN_BLK) {
        // fallback: round-1 atomic path (correct, slower)
        float* deg = (float*)d_ws;
        int n_out = n_nodes * OUT_DIM;
        int blocks = (n_out + 255) / 256;
        if (blocks > 2048) blocks = 2048;
        zero_k<<<blocks, 256, 0, stream>>>(out, deg, n_out, n_nodes);
        degf_k<<<(n_edges + 255) / 256, 256, 0, stream>>>(dst, deg, n_edges);
        long long total = (long long)n_edges * D_FEAT;
        scatter_k<<<(int)((total + 255) / 256), 256, 0, stream>>>(emb, src, dst, out, n_edges);
        prompt_k<<<(n_nodes * P_DIM + 255) / 256, 256, 0, stream>>>(w, deg, out, n_nodes);
        return;
    }

    int* hist       = (int*)d_ws;
    int* offs       = hist + n_nodes;
    int* cursor     = offs + n_nodes;
    int* aux        = cursor + n_nodes;
    int* sorted_src = aux + SCAN_BLK;

    hist0_k<<<(n_nodes + 255) / 256, 256, 0, stream>>>(hist, n_nodes);
    hist_k<<<(n_edges + 255) / 256, 256, 0, stream>>>(dst, hist, n_edges);
    scan_block_k<<<nb, SCAN_BLK, 0, stream>>>(hist, offs, aux, n_nodes);
    scan_aux_k<<<1, SCAN_BLK, 0, stream>>>(aux, nb);
    scan_add_k<<<nb, SCAN_BLK, 0, stream>>>(offs, aux, cursor, n_nodes);
    scatter_sort_k<<<(n_edges + 255) / 256, 256, 0, stream>>>(src, dst, cursor, sorted_src, n_edges);
    agg_k<<<(n_nodes + 1) / 2, 192, 0, stream>>>(emb, w, offs, hist, sorted_src, out, n_nodes);
}

// Round 4
// 139.366 us; speedup vs baseline: 2.4724x; 1.2419x over previous
//
#include <hip/hip_runtime.h>

#define D_FEAT 96
#define P_DIM 96
#define OUT_DIM 192
#define SCAN_BLK 256
#define NODES_PER_BLK 8
#define LPN 24   // lanes per node: 24 x float4 = 96 floats

typedef float f32x4 __attribute__((ext_vector_type(4)));

// ---------------- fallback (round-1) kernels: used only if ws too small ----
__global__ __launch_bounds__(256) void zero_k(float* __restrict__ out,
                                              float* __restrict__ deg,
                                              int n_out, int n_deg) {
    int stride = gridDim.x * blockDim.x;
    for (int i = blockIdx.x * blockDim.x + threadIdx.x; i < n_out; i += stride)
        out[i] = 0.0f;
    for (int i = blockIdx.x * blockDim.x + threadIdx.x; i < n_deg; i += stride)
        deg[i] = 0.0f;
}

__global__ __launch_bounds__(256) void degf_k(const int* __restrict__ dst,
                                              float* __restrict__ deg,
                                              int n_edges) {
    int e = blockIdx.x * blockDim.x + threadIdx.x;
    if (e < n_edges) atomicAdd(deg + dst[e], 1.0f);
}

__global__ __launch_bounds__(256) void scatter_k(const float* __restrict__ emb,
                                                 const int* __restrict__ src,
                                                 const int* __restrict__ dst,
                                                 float* __restrict__ out,
                                                 int n_edges) {
    int idx = blockIdx.x * blockDim.x + threadIdx.x;
    int e = idx / D_FEAT;
    if (e >= n_edges) return;
    int c = idx - e * D_FEAT;
    atomicAdd(out + (size_t)dst[e] * OUT_DIM + c, emb[(size_t)src[e] * D_FEAT + c]);
}

__global__ __launch_bounds__(256) void prompt_k(const float* __restrict__ w,
                                                const float* __restrict__ deg,
                                                float* __restrict__ out,
                                                int n_nodes) {
    int idx = blockIdx.x * blockDim.x + threadIdx.x;
    if (idx >= n_nodes * P_DIM) return;
    int v = idx / P_DIM;
    int c = idx - v * P_DIM;
    out[(size_t)v * OUT_DIM + P_DIM + c] = deg[v] * w[c];
}

// ---------------- sorted-CSR path ------------------------------------------

// hist[dst[e]]++
__global__ __launch_bounds__(256) void hist_k(const int* __restrict__ dst,
                                              int* __restrict__ hist, int n_edges) {
    int e = blockIdx.x * blockDim.x + threadIdx.x;
    if (e < n_edges) atomicAdd(hist + dst[e], 1);
}

// per-block exclusive scan; aux[b] = block sum
__global__ __launch_bounds__(SCAN_BLK) void scan_block_k(const int* __restrict__ hist,
                                                         int* __restrict__ offs,
                                                         int* __restrict__ aux, int n) {
    __shared__ int buf[SCAN_BLK];
    int t = threadIdx.x;
    int i = blockIdx.x * SCAN_BLK + t;
    int v = (i < n) ? hist[i] : 0;
    buf[t] = v;
    __syncthreads();
    for (int off = 1; off < SCAN_BLK; off <<= 1) {
        int x = (t >= off) ? buf[t - off] : 0;
        __syncthreads();
        buf[t] += x;
        __syncthreads();
    }
    if (i < n) offs[i] = buf[t] - v;          // exclusive within block
    if (t == SCAN_BLK - 1) aux[blockIdx.x] = buf[t];
}

// each block redundantly scans aux[nb] in LDS, adds its base, fills cursor
__global__ __launch_bounds__(SCAN_BLK) void scan_addcur_k(int* __restrict__ offs,
                                                          const int* __restrict__ aux,
                                                          int* __restrict__ cursor,
                                                          int n, int nb) {
    __shared__ int buf[SCAN_BLK];
    int t = threadIdx.x;
    buf[t] = (t < nb) ? aux[t] : 0;
    __syncthreads();
    for (int off = 1; off < SCAN_BLK; off <<= 1) {    // inclusive scan
        int x = (t >= off) ? buf[t - off] : 0;
        __syncthreads();
        buf[t] += x;
        __syncthreads();
    }
    int base = (blockIdx.x == 0) ? 0 : buf[blockIdx.x - 1];
    int i = blockIdx.x * SCAN_BLK + t;
    if (i < n) {
        int o = offs[i] + base;
        offs[i] = o;
        cursor[i] = o;
    }
}

// sorted_src[pos] = src[e], pos from per-dst cursor
__global__ __launch_bounds__(256) void scatter_sort_k(const int* __restrict__ src,
                                                      const int* __restrict__ dst,
                                                      int* __restrict__ cursor,
                                                      int* __restrict__ sorted_src,
                                                      int n_edges) {
    int e = blockIdx.x * blockDim.x + threadIdx.x;
    if (e < n_edges) {
        int pos = atomicAdd(cursor + dst[e], 1);
        sorted_src[pos] = src[e];
    }
}

// one node per 24 lanes, float4 gathers, 4-way unroll (64B in flight/thread)
__global__ __launch_bounds__(NODES_PER_BLK * LPN) void agg4_k(
        const f32x4* __restrict__ emb4,      // [N, 24] f32x4
        const f32x4* __restrict__ w4,        // [24] f32x4
        const int* __restrict__ offs,
        const int* __restrict__ hist,
        const int* __restrict__ sorted_src,
        float* __restrict__ out, int n_nodes) {
    int t = threadIdx.x;
    int sub = t / LPN;
    int lane = t - sub * LPN;                 // float4 column index 0..23
    int node = blockIdx.x * NODES_PER_BLK + sub;
    if (node >= n_nodes) return;

    int start = offs[node];
    int cnt = hist[node];

    f32x4 a0 = {0.f, 0.f, 0.f, 0.f};
    f32x4 a1 = a0, a2 = a0, a3 = a0;
    int j = 0;
    for (; j + 3 < cnt; j += 4) {
        int s0 = sorted_src[start + j];
        int s1 = sorted_src[start + j + 1];
        int s2 = sorted_src[start + j + 2];
        int s3 = sorted_src[start + j + 3];
        f32x4 v0 = emb4[(size_t)s0 * LPN + lane];
        f32x4 v1 = emb4[(size_t)s1 * LPN + lane];
        f32x4 v2 = emb4[(size_t)s2 * LPN + lane];
        f32x4 v3 = emb4[(size_t)s3 * LPN + lane];
        a0 += v0; a1 += v1; a2 += v2; a3 += v3;
    }
    for (; j < cnt; ++j) {
        int s0 = sorted_src[start + j];
        a0 += emb4[(size_t)s0 * LPN + lane];
    }
    f32x4 ft = (a0 + a1) + (a2 + a3);

    f32x4* outrow = (f32x4*)(out + (size_t)node * OUT_DIM);
    float c = (float)cnt;
    f32x4 pv = c * w4[lane];
    __builtin_nontemporal_store(ft, outrow + lane);
    __builtin_nontemporal_store(pv, outrow + LPN + lane);
}

extern "C" void kernel_launch(void* const* d_in, const int* in_sizes, int n_in,
                              void* d_out, int out_size, void* d_ws, size_t ws_size,
                              hipStream_t stream) {
    const float* emb = (const float*)d_in[0];   // [N, 96] f32
    const float* w   = (const float*)d_in[1];   // [1, 96] f32
    const int*   src = (const int*)d_in[2];     // [E] int32
    const int*   dst = (const int*)d_in[3];     // [E] int32
    float* out = (float*)d_out;                 // [N, 192] f32

    const int n_nodes = in_sizes[0] / D_FEAT;
    const int n_edges = in_sizes[2];
    const int nb = (n_nodes + SCAN_BLK - 1) / SCAN_BLK;

    // ws layout (int32): hist[N] | offs[N] | cursor[N] | aux[SCAN_BLK] | sorted_src[E]
    size_t need = ((size_t)3 * n_nodes + SCAN_BLK + n_edges) * sizeof(int);

    if (ws_size < need || nb > SCAN_BLK) {
        // fallback: round-1 atomic path (correct, slower)
        float* deg = (float*)d_ws;
        int n_out = n_nodes * OUT_DIM;
        int blocks = (n_out + 255) / 256;
        if (blocks > 2048) blocks = 2048;
        zero_k<<<blocks, 256, 0, stream>>>(out, deg, n_out, n_nodes);
        degf_k<<<(n_edges + 255) / 256, 256, 0, stream>>>(dst, deg, n_edges);
        long long total = (long long)n_edges * D_FEAT;
        scatter_k<<<(int)((total + 255) / 256), 256, 0, stream>>>(emb, src, dst, out, n_edges);
        prompt_k<<<(n_nodes * P_DIM + 255) / 256, 256, 0, stream>>>(w, deg, out, n_nodes);
        return;
    }

    int* hist       = (int*)d_ws;
    int* offs       = hist + n_nodes;
    int* cursor     = offs + n_nodes;
    int* aux        = cursor + n_nodes;
    int* sorted_src = aux + SCAN_BLK;

    (void)hipMemsetAsync(hist, 0, (size_t)n_nodes * sizeof(int), stream);
    hist_k<<<(n_edges + 255) / 256, 256, 0, stream>>>(dst, hist, n_edges);
    scan_block_k<<<nb, SCAN_BLK, 0, stream>>>(hist, offs, aux, n_nodes);
    scan_addcur_k<<<nb, SCAN_BLK, 0, stream>>>(offs, aux, cursor, n_nodes, nb);
    scatter_sort_k<<<(n_edges + 255) / 256, 256, 0, stream>>>(src, dst, cursor, sorted_src, n_edges);
    agg4_k<<<(n_nodes + NODES_PER_BLK - 1) / NODES_PER_BLK, NODES_PER_BLK * LPN, 0, stream>>>(
        (const f32x4*)emb, (const f32x4*)w, offs, hist, sorted_src, out, n_nodes);
}